// Round 8
// baseline (110.418 us; speedup 1.0000x reference)
//
#include <hip/hip_runtime.h>
#include <stdint.h>

#define PNUM 128
#define BATCH 8192
#define WPB 4                      // waves per block, 1 batch per wave
#define GRID1 (BATCH / WPB)        // 2048 blocks of 256 threads

typedef uint32_t u32;
typedef uint32_t u32x2 __attribute__((ext_vector_type(2)));
typedef uint32_t u32x4 __attribute__((ext_vector_type(4)));

// f32x2 -> f16x2 (RTZ) packed into one u32
__device__ __forceinline__ u32 cvt2u(float x, float y) {
    return __builtin_bit_cast(u32, __builtin_amdgcn_cvt_pkrtz(x, y));
}

#define DSR64(dst, addr) \
    asm volatile("ds_read_b64 %0, %1" : "=v"(dst) : "v"(addr))
#define DSR128(dst, addr, OFF) \
    asm volatile("ds_read_b128 %0, %1 offset:" OFF : "=v"(dst) : "v"(addr))
#define DSR2x64(dst, addr) \
    asm volatile("ds_read2_b64 %0, %1 offset0:1 offset1:2" : "=v"(dst) : "v"(addr))
#define WAITLG(N) \
    asm volatile("s_waitcnt lgkmcnt(" #N ")" ::: "memory"); \
    __builtin_amdgcn_sched_barrier(0)

// R13 = R12 done right: ALL inner asm is VOLATILE so LLVM cannot re-serialize
// the interleave (R12 post-mortem: non-volatile asm was rescheduled for min
// register pressure — VGPR stayed 28, chains restored, gain 4%). Pinned
// order: 4x pk_add, 4x and(abs), 4x pk_min, 4x pk_fma, 4x dot2; the 4 lanes
// of a quad touch 4 DIFFERENT accumulators -> every dependent pair is >=4
// instrs apart (>= ALU latency at 2cyc/instr issue). Per-accumulator dot2
// order identical to R9 -> bitwise-identical result.
#define QUAD(p0,q0,A0, p1,q1,A1, p2,q2,A2, p3,q3,A3) do { \
    u32 d0_, d1_, d2_, d3_, m0_, m1_, m2_, m3_, t0_, t1_, t2_, t3_; \
    asm volatile("v_pk_add_f16 %0, %1, %2 neg_lo:[0,1] neg_hi:[0,1]" : "=v"(d0_) : "v"(p0), "v"(q0)); \
    asm volatile("v_pk_add_f16 %0, %1, %2 neg_lo:[0,1] neg_hi:[0,1]" : "=v"(d1_) : "v"(p1), "v"(q1)); \
    asm volatile("v_pk_add_f16 %0, %1, %2 neg_lo:[0,1] neg_hi:[0,1]" : "=v"(d2_) : "v"(p2), "v"(q2)); \
    asm volatile("v_pk_add_f16 %0, %1, %2 neg_lo:[0,1] neg_hi:[0,1]" : "=v"(d3_) : "v"(p3), "v"(q3)); \
    asm volatile("v_and_b32 %0, 0x7fff7fff, %0" : "+v"(d0_)); \
    asm volatile("v_and_b32 %0, 0x7fff7fff, %0" : "+v"(d1_)); \
    asm volatile("v_and_b32 %0, 0x7fff7fff, %0" : "+v"(d2_)); \
    asm volatile("v_and_b32 %0, 0x7fff7fff, %0" : "+v"(d3_)); \
    asm volatile("v_pk_min_f16 %0, %1, %2" : "=v"(m0_) : "v"(d0_), "v"(cOne)); \
    asm volatile("v_pk_min_f16 %0, %1, %2" : "=v"(m1_) : "v"(d1_), "v"(cOne)); \
    asm volatile("v_pk_min_f16 %0, %1, %2" : "=v"(m2_) : "v"(d2_), "v"(cOne)); \
    asm volatile("v_pk_min_f16 %0, %1, %2" : "=v"(m3_) : "v"(d3_), "v"(cOne)); \
    asm volatile("v_pk_fma_f16 %0, %1, %2, %3" : "=v"(t0_) : "v"(m0_), "v"(cNegHalf), "v"(d0_)); \
    asm volatile("v_pk_fma_f16 %0, %1, %2, %3" : "=v"(t1_) : "v"(m1_), "v"(cNegHalf), "v"(d1_)); \
    asm volatile("v_pk_fma_f16 %0, %1, %2, %3" : "=v"(t2_) : "v"(m2_), "v"(cNegHalf), "v"(d2_)); \
    asm volatile("v_pk_fma_f16 %0, %1, %2, %3" : "=v"(t3_) : "v"(m3_), "v"(cNegHalf), "v"(d3_)); \
    asm volatile("v_dot2_f32_f16 %0, %1, %2, %0" : "+v"(A0) : "v"(m0_), "v"(t0_)); \
    asm volatile("v_dot2_f32_f16 %0, %1, %2, %0" : "+v"(A1) : "v"(m1_), "v"(t1_)); \
    asm volatile("v_dot2_f32_f16 %0, %1, %2, %0" : "+v"(A2) : "v"(m2_), "v"(t2_)); \
    asm volatile("v_dot2_f32_f16 %0, %1, %2, %0" : "+v"(A3) : "v"(m3_), "v"(t3_)); \
} while (0)

// One iteration = 16 units = 4 quads. Quad q holds units {q, q+4, q+8, q+12}
// -> 4 distinct accumulators per quad; same per-acc order as R9.
#define ISSUE(Bg, Bq0, Bq1) \
    DSR2x64(Bg, issGA); \
    DSR128(Bq0, issPA, "0"); \
    DSR128(Bq1, issPA, "512"); \
    issGA += 16; issPA += 16

#define COMPUTE(G, Q0, Q1, W0, W1, DO_ISSUE) \
    QUAD(Q0[0], W0,   a00,  Q0[0], W1,   a01,  Q1[0], W0,   a10,  Q1[0], W1,   a11); \
    DO_ISSUE; \
    QUAD(Q0[1], W1,   a00,  Q0[1], G[0], a01,  Q1[1], W1,   a10,  Q1[1], G[0], a11); \
    QUAD(Q0[2], G[0], a00,  Q0[2], G[1], a01,  Q1[2], G[0], a10,  Q1[2], G[1], a11); \
    QUAD(Q0[3], G[1], a00,  Q0[3], G[2], a01,  Q1[3], G[1], a10,  Q1[3], G[2], a11)

// One WAVE per batch, both preds. Lane k owns shifts {2k,2k+1}.
// Memory structure: R9/R11's verified triple-buffered asm DS pipeline,
// 3 DS ops/iter (ds_read2_b64 merged gather), linear walk, no atomics.
__global__ __launch_bounds__(64 * WPB, 8) void match_fused(
        const float* __restrict__ pred0,
        const float* __restrict__ pred1,
        const float* __restrict__ gt,
        float* __restrict__ ws) {
    __shared__ __align__(16) _Float16 lds[WPB][1024];  // ring 1024B | q0 512B | q1 512B
    __shared__ float bsum[WPB];

    const int t = threadIdx.x;
    const int k = t & 63;
    const int w = __builtin_amdgcn_readfirstlane(t >> 6);
    const int b = blockIdx.x * WPB + w;

    _Float16* base = lds[w];
    uint2* ringU = (uint2*)base;              // 128 entries (doubled ring)
    uint2* q0s   = (uint2*)(base + 512);      // byte 1024
    uint2* q1s   = (uint2*)(base + 768);      // byte 1536

    // ---- stage + f32->f16 convert (own wave's region; no barrier needed) ----
    const float4* gv4 = (const float4*)(gt    + (size_t)b * (PNUM * 2));
    const float4* p0v = (const float4*)(pred0 + (size_t)b * (PNUM * 2));
    const float4* p1v = (const float4*)(pred1 + (size_t)b * (PNUM * 2));
    {
        float4 g = gv4[k];
        uint2 gh = {cvt2u(g.x, g.y), cvt2u(g.z, g.w)};
        ringU[k] = gh; ringU[k + 64] = gh;
        float4 p = p0v[k];
        q0s[k] = (uint2){cvt2u(p.x, p.y), cvt2u(p.z, p.w)};
        p = p1v[k];
        q1s[k] = (uint2){cvt2u(p.x, p.y), cvt2u(p.z, p.w)};
    }

    // raw LDS byte addresses for asm DS ops
    const u32 ldsb = (u32)(uintptr_t)base;
    u32 issGA = ldsb + (u32)(k * 8);   // ring gather base (lane-sliding)
    u32 issPA = ldsb + 1024;           // pred broadcast base (wave-uniform)

    // drain staging ds_writes before asm reads
    asm volatile("s_waitcnt lgkmcnt(0)" ::: "memory");
    __builtin_amdgcn_sched_barrier(0);

    const u32 cOne = 0x3C003C00u;      // packed f16 {1.0, 1.0}
    const u32 cNegHalf = 0xB800B800u;  // packed f16 {-0.5, -0.5}

    // ---- prologue: W(iter0)=ring[k]; issue iter0 (buf0), iter1 (buf1) ----
    u32x2 Wsp;
    DSR64(Wsp, issGA);                 // seed W; issGA unchanged (offset 0)
    u32x4 b0g, b0q0, b0q1, b1g, b1q0, b1q1, b2g, b2q0, b2q1;
    ISSUE(b0g, b0q0, b0q1);            // iter 0
    ISSUE(b1g, b1q0, b1q1);            // iter 1
    // outstanding: Wsp(1) + iter0(3) + iter1(3) = 7

    float a00 = 0.f, a01 = 0.f, a10 = 0.f, a11 = 0.f;

    // ---- peeled first trio (W chain seeded from Wsp) ----
    WAITLG(3); COMPUTE(b0g, b0q0, b0q1, Wsp[0], Wsp[1], ISSUE(b2g, b2q0, b2q1));
    WAITLG(3); COMPUTE(b1g, b1q0, b1q1, b0g[2], b0g[3], ISSUE(b0g, b0q0, b0q1));
    WAITLG(3); COMPUTE(b2g, b2q0, b2q1, b1g[2], b1g[3], ISSUE(b1g, b1q0, b1q1));

#pragma unroll 1
    for (int tr = 0; tr < 9; ++tr) {   // iters 3..29
        WAITLG(3); COMPUTE(b0g, b0q0, b0q1, b2g[2], b2g[3], ISSUE(b2g, b2q0, b2q1));
        WAITLG(3); COMPUTE(b1g, b1q0, b1q1, b0g[2], b0g[3], ISSUE(b0g, b0q0, b0q1));
        WAITLG(3); COMPUTE(b2g, b2q0, b2q1, b1g[2], b1g[3], ISSUE(b1g, b1q0, b1q1));
    }
    // ---- epilogue: iters 30 (b0), 31 (b1) ----
    WAITLG(3); COMPUTE(b0g, b0q0, b0q1, b2g[2], b2g[3], );
    WAITLG(0); COMPUTE(b1g, b1q0, b1q1, b0g[2], b0g[3], );

    // per-pred min over lane's 2 shifts, then over the wave
    float r0 = fminf(a00, a01);
    float r1 = fminf(a10, a11);
#pragma unroll
    for (int m = 32; m > 0; m >>= 1) {
        r0 = fminf(r0, __shfl_xor(r0, m, 64));
        r1 = fminf(r1, __shfl_xor(r1, m, 64));
    }

    if (k == 0) bsum[w] = r0 + r1;
    __syncthreads();
    if (t == 0) {
        // plain store, 2048 distinct addresses -> no cross-XCD RMW chain
        ws[blockIdx.x] = bsum[0] + bsum[1] + bsum[2] + bsum[3];
    }
}

// Second dispatch: sum 2048 per-block partials, scale, write out.
__global__ __launch_bounds__(256) void reduce_out(
        const float* __restrict__ ws, float* __restrict__ out) {
    const int t = threadIdx.x;
    const float4* w4 = (const float4*)ws;
    float4 v0 = w4[t];           // 256 * 4 = 1024 partials
    float4 v1 = w4[t + 256];     // + 1024 = 2048
    float s = ((v0.x + v0.y) + (v0.z + v0.w)) + ((v1.x + v1.y) + (v1.z + v1.w));
#pragma unroll
    for (int m = 32; m > 0; m >>= 1) s += __shfl_xor(s, m, 64);
    __shared__ float acc[4];
    const int w = t >> 6;
    if ((t & 63) == 0) acc[w] = s;
    __syncthreads();
    if (t == 0)
        out[0] = (acc[0] + acc[1] + acc[2] + acc[3]) * (1.0f / (2.0f * BATCH * PNUM));
}

extern "C" void kernel_launch(void* const* d_in, const int* in_sizes, int n_in,
                              void* d_out, int out_size, void* d_ws, size_t ws_size,
                              hipStream_t stream) {
    const float* pred0 = (const float*)d_in[0];
    const float* pred1 = (const float*)d_in[1];
    const float* gt    = (const float*)d_in[2];
    float* out = (float*)d_out;
    float* ws  = (float*)d_ws;      // 2048 floats = 8 KB of workspace

    match_fused<<<GRID1, 64 * WPB, 0, stream>>>(pred0, pred1, gt, ws);
    reduce_out<<<1, 256, 0, stream>>>(ws, out);
}

// Round 9
// 108.578 us; speedup vs baseline: 1.0170x; 1.0170x over previous
//
#include <hip/hip_runtime.h>
#include <stdint.h>

#define PNUM 128
#define BATCH 8192
#define WPB 4                      // waves per block, 1 batch per wave
#define GRID1 (BATCH / WPB)        // 2048 blocks of 256 threads

typedef uint32_t u32;
typedef uint32_t u32x2 __attribute__((ext_vector_type(2)));
typedef uint32_t u32x4 __attribute__((ext_vector_type(4)));

// f32x2 -> f16x2 (RTZ) packed into one u32
__device__ __forceinline__ u32 cvt2u(float x, float y) {
    return __builtin_bit_cast(u32, __builtin_amdgcn_cvt_pkrtz(x, y));
}

// R14: volatile-pinned interleaved quad (R13-verified: bitwise-identical,
// independent adjacent instrs). 4 units stage-by-stage, 4 distinct accs.
#define QUAD(p0,q0,A0, p1,q1,A1, p2,q2,A2, p3,q3,A3) do { \
    u32 d0_, d1_, d2_, d3_, m0_, m1_, m2_, m3_, t0_, t1_, t2_, t3_; \
    asm volatile("v_pk_add_f16 %0, %1, %2 neg_lo:[0,1] neg_hi:[0,1]" : "=v"(d0_) : "v"(p0), "v"(q0)); \
    asm volatile("v_pk_add_f16 %0, %1, %2 neg_lo:[0,1] neg_hi:[0,1]" : "=v"(d1_) : "v"(p1), "v"(q1)); \
    asm volatile("v_pk_add_f16 %0, %1, %2 neg_lo:[0,1] neg_hi:[0,1]" : "=v"(d2_) : "v"(p2), "v"(q2)); \
    asm volatile("v_pk_add_f16 %0, %1, %2 neg_lo:[0,1] neg_hi:[0,1]" : "=v"(d3_) : "v"(p3), "v"(q3)); \
    asm volatile("v_and_b32 %0, 0x7fff7fff, %0" : "+v"(d0_)); \
    asm volatile("v_and_b32 %0, 0x7fff7fff, %0" : "+v"(d1_)); \
    asm volatile("v_and_b32 %0, 0x7fff7fff, %0" : "+v"(d2_)); \
    asm volatile("v_and_b32 %0, 0x7fff7fff, %0" : "+v"(d3_)); \
    asm volatile("v_pk_min_f16 %0, %1, %2" : "=v"(m0_) : "v"(d0_), "v"(cOne)); \
    asm volatile("v_pk_min_f16 %0, %1, %2" : "=v"(m1_) : "v"(d1_), "v"(cOne)); \
    asm volatile("v_pk_min_f16 %0, %1, %2" : "=v"(m2_) : "v"(d2_), "v"(cOne)); \
    asm volatile("v_pk_min_f16 %0, %1, %2" : "=v"(m3_) : "v"(d3_), "v"(cOne)); \
    asm volatile("v_pk_fma_f16 %0, %1, %2, %3" : "=v"(t0_) : "v"(m0_), "v"(cNegHalf), "v"(d0_)); \
    asm volatile("v_pk_fma_f16 %0, %1, %2, %3" : "=v"(t1_) : "v"(m1_), "v"(cNegHalf), "v"(d1_)); \
    asm volatile("v_pk_fma_f16 %0, %1, %2, %3" : "=v"(t2_) : "v"(m2_), "v"(cNegHalf), "v"(d2_)); \
    asm volatile("v_pk_fma_f16 %0, %1, %2, %3" : "=v"(t3_) : "v"(m3_), "v"(cNegHalf), "v"(d3_)); \
    asm volatile("v_dot2_f32_f16 %0, %1, %2, %0" : "+v"(A0) : "v"(m0_), "v"(t0_)); \
    asm volatile("v_dot2_f32_f16 %0, %1, %2, %0" : "+v"(A1) : "v"(m1_), "v"(t1_)); \
    asm volatile("v_dot2_f32_f16 %0, %1, %2, %0" : "+v"(A2) : "v"(m2_), "v"(t2_)); \
    asm volatile("v_dot2_f32_f16 %0, %1, %2, %0" : "+v"(A3) : "v"(m3_), "v"(t3_)); \
} while (0)

// R14 changes vs R13 (wall-busy gap attack; count/order of VALU math ops
// unchanged): (1) FULLY UNROLLED loop, ALL DS offsets immediate ("i"/%c
// asm operands) -> zero address arithmetic, zero loop overhead in the hot
// path; (2) prefetch depth 3 (4 buffers, 9 loads outstanding, steady-state
// lgkmcnt(6)) to absorb per-CU DS queue jitter from 32 bursting waves.
__global__ __launch_bounds__(64 * WPB, 6) void match_fused(
        const float* __restrict__ pred0,
        const float* __restrict__ pred1,
        const float* __restrict__ gt,
        float* __restrict__ ws) {
    __shared__ __align__(16) _Float16 lds[WPB][1024];  // ring 1024B | q0 512B | q1 512B
    __shared__ float bsum[WPB];

    const int t = threadIdx.x;
    const int k = t & 63;
    const int w = __builtin_amdgcn_readfirstlane(t >> 6);
    const int b = blockIdx.x * WPB + w;

    _Float16* base = lds[w];
    uint2* ringU = (uint2*)base;              // 128 entries (doubled ring)
    uint2* q0s   = (uint2*)(base + 512);      // byte 1024
    uint2* q1s   = (uint2*)(base + 768);      // byte 1536

    // ---- stage + f32->f16 convert (own wave's region; no barrier needed) ----
    const float4* gv4 = (const float4*)(gt    + (size_t)b * (PNUM * 2));
    const float4* p0v = (const float4*)(pred0 + (size_t)b * (PNUM * 2));
    const float4* p1v = (const float4*)(pred1 + (size_t)b * (PNUM * 2));
    {
        float4 g = gv4[k];
        uint2 gh = {cvt2u(g.x, g.y), cvt2u(g.z, g.w)};
        ringU[k] = gh; ringU[k + 64] = gh;
        float4 p = p0v[k];
        q0s[k] = (uint2){cvt2u(p.x, p.y), cvt2u(p.z, p.w)};
        p = p1v[k];
        q1s[k] = (uint2){cvt2u(p.x, p.y), cvt2u(p.z, p.w)};
    }

    // raw LDS byte addresses for asm DS ops
    const u32 ldsb = (u32)(uintptr_t)base;
    u32 gA = ldsb + (u32)(k * 8);   // ring gather base (lane-sliding)
    u32 pA = ldsb;                  // broadcast base; offsets 1024+/1536+ imm

    // same-wave DS is program-ordered; belt-and-braces drain of staging
    asm volatile("s_waitcnt lgkmcnt(0)" ::: "memory");
    __builtin_amdgcn_sched_barrier(0);

    const u32 cOne = 0x3C003C00u;      // packed f16 {1.0, 1.0}
    const u32 cNegHalf = 0xB800B800u;  // packed f16 {-0.5, -0.5}

    // ---- prologue: seed W(0)=ring[k]; issue iters 0,1,2 (depth 3) ----
    u32x2 Wsp;
    asm volatile("ds_read_b64 %0, %1" : "=v"(Wsp) : "v"(gA));
    u32x4 G[4], Q0[4], Q1[4];
#pragma unroll
    for (int h = 0; h < 3; ++h) {
        asm volatile("ds_read2_b64 %0, %1 offset0:%c2 offset1:%c3"
                     : "=v"(G[h]) : "v"(gA), "i"(2 * h + 1), "i"(2 * h + 2));
        asm volatile("ds_read_b128 %0, %1 offset:%c2"
                     : "=v"(Q0[h]) : "v"(pA), "i"(1024 + 16 * h));
        asm volatile("ds_read_b128 %0, %1 offset:%c2"
                     : "=v"(Q1[h]) : "v"(pA), "i"(1536 + 16 * h));
    }
    // outstanding: seed(1) + 3 iters x 3 = 10

    float a00 = 0.f, a01 = 0.f, a10 = 0.f, a11 = 0.f;

#pragma unroll
    for (int h = 0; h < 32; ++h) {
        const int cur = h & 3;
        const int prv = (h + 3) & 3;       // (h-1) mod 4; also the issue target
        // steady state: {h,h+1,h+2} outstanding (9); wait until h's 3 done
        asm volatile("s_waitcnt lgkmcnt(%c0)"
                     :: "i"(h == 31 ? 0 : (h == 30 ? 3 : 6)) : "memory");
        __builtin_amdgcn_sched_barrier(0);

        const u32 W0 = (h == 0) ? Wsp[0] : G[prv][2];
        const u32 W1 = (h == 0) ? Wsp[1] : G[prv][3];

        QUAD(Q0[cur][0], W0, a00,  Q0[cur][0], W1,        a01,
             Q1[cur][0], W0, a10,  Q1[cur][0], W1,        a11);
        QUAD(Q0[cur][1], W1, a00,  Q0[cur][1], G[cur][0], a01,
             Q1[cur][1], W1, a10,  Q1[cur][1], G[cur][0], a11);

        // issue iter h+3 into buffer prv (W fully consumed above)
        if (h < 29) {
            asm volatile("ds_read2_b64 %0, %1 offset0:%c2 offset1:%c3"
                         : "=v"(G[prv]) : "v"(gA), "i"(2 * (h + 3) + 1), "i"(2 * (h + 3) + 2));
            asm volatile("ds_read_b128 %0, %1 offset:%c2"
                         : "=v"(Q0[prv]) : "v"(pA), "i"(1024 + 16 * (h + 3)));
            asm volatile("ds_read_b128 %0, %1 offset:%c2"
                         : "=v"(Q1[prv]) : "v"(pA), "i"(1536 + 16 * (h + 3)));
        }

        QUAD(Q0[cur][2], G[cur][0], a00,  Q0[cur][2], G[cur][1], a01,
             Q1[cur][2], G[cur][0], a10,  Q1[cur][2], G[cur][1], a11);
        QUAD(Q0[cur][3], G[cur][1], a00,  Q0[cur][3], G[cur][2], a01,
             Q1[cur][3], G[cur][1], a10,  Q1[cur][3], G[cur][2], a11);
    }

    // per-pred min over lane's 2 shifts, then over the wave
    float r0 = fminf(a00, a01);
    float r1 = fminf(a10, a11);
#pragma unroll
    for (int m = 32; m > 0; m >>= 1) {
        r0 = fminf(r0, __shfl_xor(r0, m, 64));
        r1 = fminf(r1, __shfl_xor(r1, m, 64));
    }

    if (k == 0) bsum[w] = r0 + r1;
    __syncthreads();
    if (t == 0) {
        // plain store, 2048 distinct addresses -> no cross-XCD RMW chain
        ws[blockIdx.x] = bsum[0] + bsum[1] + bsum[2] + bsum[3];
    }
}

// Second dispatch: sum 2048 per-block partials, scale, write out.
__global__ __launch_bounds__(256) void reduce_out(
        const float* __restrict__ ws, float* __restrict__ out) {
    const int t = threadIdx.x;
    const float4* w4 = (const float4*)ws;
    float4 v0 = w4[t];           // 256 * 4 = 1024 partials
    float4 v1 = w4[t + 256];     // + 1024 = 2048
    float s = ((v0.x + v0.y) + (v0.z + v0.w)) + ((v1.x + v1.y) + (v1.z + v1.w));
#pragma unroll
    for (int m = 32; m > 0; m >>= 1) s += __shfl_xor(s, m, 64);
    __shared__ float acc[4];
    const int w = t >> 6;
    if ((t & 63) == 0) acc[w] = s;
    __syncthreads();
    if (t == 0)
        out[0] = (acc[0] + acc[1] + acc[2] + acc[3]) * (1.0f / (2.0f * BATCH * PNUM));
}

extern "C" void kernel_launch(void* const* d_in, const int* in_sizes, int n_in,
                              void* d_out, int out_size, void* d_ws, size_t ws_size,
                              hipStream_t stream) {
    const float* pred0 = (const float*)d_in[0];
    const float* pred1 = (const float*)d_in[1];
    const float* gt    = (const float*)d_in[2];
    float* out = (float*)d_out;
    float* ws  = (float*)d_ws;      // 2048 floats = 8 KB of workspace

    match_fused<<<GRID1, 64 * WPB, 0, stream>>>(pred0, pred1, gt, ws);
    reduce_out<<<1, 256, 0, stream>>>(ws, out);
}